// Round 6
// baseline (204.875 us; speedup 1.0000x reference)
//
#include <hip/hip_runtime.h>
#include <math.h>

#define DEG2RAD 0.017453292519943295f
#define EARTH_R 6371.009
#define PI_F    3.14159265358979f
#define PIO2_F  1.57079632679490f

// Native clang vector type (keeps single-instr dwordx4 codegen)
typedef float vf4 __attribute__((ext_vector_type(4)));

// atan2(num, den) with num >= 0 (num = sqrt(...)). num^2+den^2 ~= 1 so
// max(num,|den|) >= ~0.707 -> raw v_rcp_f32 safe.
__device__ __forceinline__ float atan2_pos(float num, float den) {
    float ad = __builtin_fabsf(den);
    float mn = fminf(num, ad);
    float mx = fmaxf(num, ad);
    float t  = mn * __builtin_amdgcn_rcpf(mx);
    float u  = t * t;
    float a  = t * (0.99997726f + u * (-0.33262347f + u * (0.19354346f +
               u * (-0.11643287f + u * (0.05265332f + u * (-0.01172120f))))));
    a = (num > ad)   ? (PIO2_F - a) : a;
    a = (den < 0.0f) ? (PI_F  - a) : a;
    return a;  // central angle; EARTH_R applied in finalize
}

__device__ __forceinline__ float gd_one(float plat, float plng, float tlat, float tlng) {
    float lat1 = fminf(fmaxf(plat, -90.0f), 90.0f) * DEG2RAD;
    float lng1 = plng * DEG2RAD;
    float lat2 = tlat * DEG2RAD;
    float lng2 = tlng * DEG2RAD;

    float s1 = __sinf(lat1), c1 = __cosf(lat1);
    float s2 = __sinf(lat2), c2 = __cosf(lat2);
    float d  = lng2 - lng1;
    float cd = __cosf(d),  sd = __sinf(d);

    float t0 = c2 * sd;
    float t1 = c1 * s2 - s1 * c2 * cd;
    float num = __builtin_amdgcn_sqrtf(t0 * t0 + t1 * t1);
    float den = s1 * s2 + c1 * c2 * cd;
    return atan2_pos(num, den);
}

// 4 float4s (8 rows) per thread; ALL 12 loads pinned in-flight before compute.
// Plain (cache-retaining) loads: ~half the 201 MB stays in Infinity Cache
// across replays, serving faster than HBM.
__global__ __launch_bounds__(256, 4) void gd_main(
    const vf4* __restrict__ pred,
    const vf4* __restrict__ tru,
    const vf4* __restrict__ site,
    const float* __restrict__ mean_speed,
    const float* __restrict__ std_speed,
    const float* __restrict__ mean,
    const float* __restrict__ stdv,
    float*       __restrict__ partials)
{
    const float ms0 = mean_speed[0], ms1 = mean_speed[1];
    const float ss0 = std_speed[0],  ss1 = std_speed[1];
    const float m0  = mean[0],       m1  = mean[1];
    const float s0  = stdv[0],       s1  = stdv[1];

    const int base = blockIdx.x * 1024 + threadIdx.x;  // block tile: 1024 float4s/array

    // --- 12-wide load burst, pinned by sched_barrier (compiler cannot sink) ---
    vf4 p0 = pred[base];
    vf4 p1 = pred[base + 256];
    vf4 p2 = pred[base + 512];
    vf4 p3 = pred[base + 768];
    vf4 t0 = tru [base];
    vf4 t1 = tru [base + 256];
    vf4 t2 = tru [base + 512];
    vf4 t3 = tru [base + 768];
    vf4 q0 = site[base];
    vf4 q1 = site[base + 256];
    vf4 q2 = site[base + 512];
    vf4 q3 = site[base + 768];
    __builtin_amdgcn_sched_barrier(0);   // nothing moves across this point

    float local = 0.0f;
    #define DO_PAIR(P, T, Q)                                                         \
    {                                                                                \
        float sa = (Q).x * s0 + m0, sb = (Q).y * s1 + m1;                            \
        float sc = (Q).z * s0 + m0, sd_ = (Q).w * s1 + m1;                           \
        local += gd_one((P).x * ss0 + ms0 + sa,  (P).y * ss1 + ms1 + sb,             \
                        (T).x * ss0 + ms0 + sa,  (T).y * ss1 + ms1 + sb);            \
        local += gd_one((P).z * ss0 + ms0 + sc,  (P).w * ss1 + ms1 + sd_,            \
                        (T).z * ss0 + ms0 + sc,  (T).w * ss1 + ms1 + sd_);           \
    }
    DO_PAIR(p0, t0, q0)
    DO_PAIR(p1, t1, q1)
    DO_PAIR(p2, t2, q2)
    DO_PAIR(p3, t3, q3)
    #undef DO_PAIR

    #pragma unroll
    for (int off = 32; off > 0; off >>= 1)
        local += __shfl_down(local, off, 64);

    __shared__ float wsum[4];
    const int lane = threadIdx.x & 63;
    const int wid  = threadIdx.x >> 6;
    if (lane == 0) wsum[wid] = local;
    __syncthreads();
    if (threadIdx.x == 0)
        partials[blockIdx.x] = wsum[0] + wsum[1] + wsum[2] + wsum[3];
}

__global__ __launch_bounds__(256) void gd_final(
    const float* __restrict__ partials, int n,
    float* __restrict__ out, double scale)   // scale = EARTH_R / B
{
    double local = 0.0;
    for (int i = threadIdx.x; i < n; i += 256)
        local += (double)partials[i];

    #pragma unroll
    for (int off = 32; off > 0; off >>= 1)
        local += __shfl_down(local, off, 64);

    __shared__ double wsum[4];
    const int lane = threadIdx.x & 63;
    const int wid  = threadIdx.x >> 6;
    if (lane == 0) wsum[wid] = local;
    __syncthreads();
    if (threadIdx.x == 0)
        out[0] = (float)((wsum[0] + wsum[1] + wsum[2] + wsum[3]) * scale);
}

extern "C" void kernel_launch(void* const* d_in, const int* in_sizes, int n_in,
                              void* d_out, int out_size, void* d_ws, size_t ws_size,
                              hipStream_t stream) {
    const vf4*  pred = (const vf4*)d_in[0];
    const vf4*  tru  = (const vf4*)d_in[1];
    const float* msp = (const float*)d_in[2];
    const float* ssp = (const float*)d_in[3];
    const vf4*  site = (const vf4*)d_in[4];
    const float* mn  = (const float*)d_in[5];
    const float* sd  = (const float*)d_in[6];

    const int total = in_sizes[0];       // B*2 floats
    const int n4    = total / 4;         // float4 count
    const long long B = total / 2;
    const int blocks = n4 / 1024;        // 4 float4s/thread/array, 256 threads

    float* partials = (float*)d_ws;      // every slot written, no init needed

    gd_main<<<blocks, 256, 0, stream>>>(pred, tru, site, msp, ssp, mn, sd, partials);
    gd_final<<<1, 256, 0, stream>>>(partials, blocks, (float*)d_out,
                                    EARTH_R / (double)B);
}

// Round 7
// 184.048 us; speedup vs baseline: 1.1132x; 1.1132x over previous
//
#include <hip/hip_runtime.h>
#include <math.h>

#define DEG2RAD 0.017453292519943295f
#define EARTH_R 6371.009
#define PI_F    3.14159265358979f
#define PIO2_F  1.57079632679490f

// Native clang vector type — required by __builtin_nontemporal_load
typedef float vf4 __attribute__((ext_vector_type(4)));

// atan2(num, den) with num >= 0 (num = sqrt(...)). num^2+den^2 ~= 1 so
// max(num,|den|) >= ~0.707 -> raw v_rcp_f32 safe.
__device__ __forceinline__ float atan2_pos(float num, float den) {
    float ad = __builtin_fabsf(den);
    float mn = fminf(num, ad);
    float mx = fmaxf(num, ad);
    float t  = mn * __builtin_amdgcn_rcpf(mx);
    float u  = t * t;
    float a  = t * (0.99997726f + u * (-0.33262347f + u * (0.19354346f +
               u * (-0.11643287f + u * (0.05265332f + u * (-0.01172120f))))));
    a = (num > ad)   ? (PIO2_F - a) : a;
    a = (den < 0.0f) ? (PI_F  - a) : a;
    return a;  // central angle; EARTH_R applied in finalize
}

__device__ __forceinline__ float gd_one(float plat, float plng, float tlat, float tlng) {
    float lat1 = fminf(fmaxf(plat, -90.0f), 90.0f) * DEG2RAD;
    float lng1 = plng * DEG2RAD;
    float lat2 = tlat * DEG2RAD;
    float lng2 = tlng * DEG2RAD;

    float s1 = __sinf(lat1), c1 = __cosf(lat1);
    float s2 = __sinf(lat2), c2 = __cosf(lat2);
    float d  = lng2 - lng1;
    float cd = __cosf(d),  sd = __sinf(d);

    float t0 = c2 * sd;
    float t1 = c1 * s2 - s1 * c2 * cd;
    float num = __builtin_amdgcn_sqrtf(t0 * t0 + t1 * t1);
    float den = s1 * s2 + c1 * c2 * cd;
    return atan2_pos(num, den);
}

// 4 float4s (8 rows) per thread; ALL 12 loads in flight before compute.
// NOTE: the nontemporal flag is what KEEPS the burst intact — with plain
// loads the compiler sinks loads to uses (VGPR=32, 72 us, R3/R6 evidence);
// with nt metadata the 12-wide burst survives and the kernel runs at the
// streaming-read floor (R5 evidence). Do not remove.
__global__ __launch_bounds__(256, 4) void gd_main(
    const vf4* __restrict__ pred,
    const vf4* __restrict__ tru,
    const vf4* __restrict__ site,
    const float* __restrict__ mean_speed,
    const float* __restrict__ std_speed,
    const float* __restrict__ mean,
    const float* __restrict__ stdv,
    float*       __restrict__ partials)
{
    const float ms0 = mean_speed[0], ms1 = mean_speed[1];
    const float ss0 = std_speed[0],  ss1 = std_speed[1];
    const float m0  = mean[0],       m1  = mean[1];
    const float s0  = stdv[0],       s1  = stdv[1];

    const int base = blockIdx.x * 1024 + threadIdx.x;  // block tile: 1024 float4s/array

    vf4 p0 = __builtin_nontemporal_load(&pred[base]);
    vf4 p1 = __builtin_nontemporal_load(&pred[base + 256]);
    vf4 p2 = __builtin_nontemporal_load(&pred[base + 512]);
    vf4 p3 = __builtin_nontemporal_load(&pred[base + 768]);
    vf4 t0 = __builtin_nontemporal_load(&tru [base]);
    vf4 t1 = __builtin_nontemporal_load(&tru [base + 256]);
    vf4 t2 = __builtin_nontemporal_load(&tru [base + 512]);
    vf4 t3 = __builtin_nontemporal_load(&tru [base + 768]);
    vf4 q0 = __builtin_nontemporal_load(&site[base]);
    vf4 q1 = __builtin_nontemporal_load(&site[base + 256]);
    vf4 q2 = __builtin_nontemporal_load(&site[base + 512]);
    vf4 q3 = __builtin_nontemporal_load(&site[base + 768]);
    __builtin_amdgcn_sched_barrier(0);   // belt-and-suspenders with nt metadata

    float local = 0.0f;
    #define DO_PAIR(P, T, Q)                                                         \
    {                                                                                \
        float sa = (Q).x * s0 + m0, sb = (Q).y * s1 + m1;                            \
        float sc = (Q).z * s0 + m0, sd_ = (Q).w * s1 + m1;                           \
        local += gd_one((P).x * ss0 + ms0 + sa,  (P).y * ss1 + ms1 + sb,             \
                        (T).x * ss0 + ms0 + sa,  (T).y * ss1 + ms1 + sb);            \
        local += gd_one((P).z * ss0 + ms0 + sc,  (P).w * ss1 + ms1 + sd_,            \
                        (T).z * ss0 + ms0 + sc,  (T).w * ss1 + ms1 + sd_);           \
    }
    DO_PAIR(p0, t0, q0)
    DO_PAIR(p1, t1, q1)
    DO_PAIR(p2, t2, q2)
    DO_PAIR(p3, t3, q3)
    #undef DO_PAIR

    #pragma unroll
    for (int off = 32; off > 0; off >>= 1)
        local += __shfl_down(local, off, 64);

    __shared__ float wsum[4];
    const int lane = threadIdx.x & 63;
    const int wid  = threadIdx.x >> 6;
    if (lane == 0) wsum[wid] = local;
    __syncthreads();
    if (threadIdx.x == 0)
        partials[blockIdx.x] = wsum[0] + wsum[1] + wsum[2] + wsum[3];
}

__global__ __launch_bounds__(256) void gd_final(
    const float* __restrict__ partials, int n,
    float* __restrict__ out, double scale)   // scale = EARTH_R / B
{
    double local = 0.0;
    for (int i = threadIdx.x; i < n; i += 256)
        local += (double)partials[i];

    #pragma unroll
    for (int off = 32; off > 0; off >>= 1)
        local += __shfl_down(local, off, 64);

    __shared__ double wsum[4];
    const int lane = threadIdx.x & 63;
    const int wid  = threadIdx.x >> 6;
    if (lane == 0) wsum[wid] = local;
    __syncthreads();
    if (threadIdx.x == 0)
        out[0] = (float)((wsum[0] + wsum[1] + wsum[2] + wsum[3]) * scale);
}

extern "C" void kernel_launch(void* const* d_in, const int* in_sizes, int n_in,
                              void* d_out, int out_size, void* d_ws, size_t ws_size,
                              hipStream_t stream) {
    const vf4*  pred = (const vf4*)d_in[0];
    const vf4*  tru  = (const vf4*)d_in[1];
    const float* msp = (const float*)d_in[2];
    const float* ssp = (const float*)d_in[3];
    const vf4*  site = (const vf4*)d_in[4];
    const float* mn  = (const float*)d_in[5];
    const float* sd  = (const float*)d_in[6];

    const int total = in_sizes[0];       // B*2 floats
    const int n4    = total / 4;         // float4 count
    const long long B = total / 2;
    const int blocks = n4 / 1024;        // 4 float4s/thread/array, 256 threads

    float* partials = (float*)d_ws;      // every slot written, no init needed

    gd_main<<<blocks, 256, 0, stream>>>(pred, tru, site, msp, ssp, mn, sd, partials);
    gd_final<<<1, 256, 0, stream>>>(partials, blocks, (float*)d_out,
                                    EARTH_R / (double)B);
}